// Round 1
// baseline (184.164 us; speedup 1.0000x reference)
//
#include <hip/hip_runtime.h>
#include <hip/hip_bf16.h>

// MultiHeadAttention fused forward, MI355X/gfx950.
// B=2, S=2048, D_IN=768, H=12, D=64.  out[b,s,h*64+e] fp32.
//
// Pipeline (all on `stream`):
//   1. prep_wt : W[h,d,e] fp32 -> Wt[w,h,e,d] bf16   (K-contiguous B operand)
//   2. proj_qkv: x @ {Wq,Wk,Wv} -> Q,K,V bf16 [B,H,S,64]  (MFMA 16x16x32 bf16)
//   3. attn    : flash attention with online softmax, causal
//
// Workspace layout (bytes):
//   Wt : [0, 3538944)              3*12*64*768 bf16
//   Q  : [3538944,  9830400)       2*12*2048*64 bf16
//   K  : [9830400,  16121856)
//   V  : [16121856, 22413312)

typedef short bf16x8 __attribute__((ext_vector_type(8)));
typedef float f32x4  __attribute__((ext_vector_type(4)));

#define MFMA16(a, b, c) __builtin_amdgcn_mfma_f32_16x16x32_bf16((a), (b), (c), 0, 0, 0)

// round-to-nearest-even fp32 -> bf16 (finite inputs)
static __device__ __forceinline__ unsigned short f2bf(float f) {
    unsigned int u = __builtin_bit_cast(unsigned int, f);
    u += 0x7fffu + ((u >> 16) & 1u);
    return (unsigned short)(u >> 16);
}

// XOR swizzle for [row][128B] LDS tiles: kills the 16-way bank conflict on
// ds_read_b128 column slices (G4).  Preserves 16B-block contiguity since the
// XOR only flips bits 4..6.
static __device__ __forceinline__ int sw(int row, int cb) {
    return (row << 7) + (cb ^ ((row & 7) << 4));
}

// ---------------------------------------------------------------------------
// Kernel 1: W[h][d][e] fp32 -> Wt[(w*12+h)*64+e][768 d] bf16   (grid 36)
// ---------------------------------------------------------------------------
__global__ __launch_bounds__(256) void prep_wt(const float* __restrict__ Wq,
                                               const float* __restrict__ Wk,
                                               const float* __restrict__ Wv,
                                               unsigned short* __restrict__ wt) {
    __shared__ float tile[64][65];  // +1 pad: conflict-free column reads
    const int w = blockIdx.x / 12, h = blockIdx.x % 12;
    const float* W = (w == 0) ? Wq : (w == 1) ? Wk : Wv;
    const int t = threadIdx.x;
    for (int dt = 0; dt < 12; ++dt) {
        for (int i = 0; i < 4; ++i) {
            int c = t + i * 256;
            int d = c >> 4, e4 = (c & 15) * 4;
            const float4 v = *(const float4*)(W + (size_t)(h * 768 + dt * 64 + d) * 64 + e4);
            tile[d][e4 + 0] = v.x; tile[d][e4 + 1] = v.y;
            tile[d][e4 + 2] = v.z; tile[d][e4 + 3] = v.w;
        }
        __syncthreads();
        for (int i = 0; i < 4; ++i) {
            int c = t + i * 256;
            int e = c >> 4, d4 = (c & 15) * 4;
            ushort4 o;
            o.x = f2bf(tile[d4 + 0][e]); o.y = f2bf(tile[d4 + 1][e]);
            o.z = f2bf(tile[d4 + 2][e]); o.w = f2bf(tile[d4 + 3][e]);
            *(ushort4*)(wt + (size_t)((w * 12 + h) * 64 + e) * 768 + dt * 64 + d4) = o;
        }
        __syncthreads();
    }
}

// ---------------------------------------------------------------------------
// Kernel 2: QKV projection.  grid (64 m-tiles, 12 heads), 256 thr = 4 waves.
// Tile: 64 s-rows x 64 e-cols x3 weights, K=768 in 64-steps.
// Wave (wr,wc) owns the 32x32 quadrant; 2x2 fragments of 16x16x32 MFMA.
// ---------------------------------------------------------------------------
__global__ __launch_bounds__(256) void proj_qkv(const float* __restrict__ x,
                                                const unsigned short* __restrict__ wt,
                                                unsigned short* __restrict__ q,
                                                unsigned short* __restrict__ k,
                                                unsigned short* __restrict__ v) {
    __shared__ char smem[4 * 8192];  // A tile + 3 B tiles, all swizzled [64][128B]
    char* Alds = smem;

    const int tile = blockIdx.x;   // 0..63 over B*S/64
    const int h = blockIdx.y;      // 0..11
    const int t = threadIdx.x;
    const int wave = t >> 6, lane = t & 63;
    const int lhi = lane >> 4, llo = lane & 15;
    const int wr = wave >> 1, wc = wave & 1;

    f32x4 acc[3][2][2] = {};

    for (int kb = 0; kb < 768; kb += 64) {
        if (kb) __syncthreads();
        // stage A: x[64 rows][64 k] fp32 -> bf16 swizzled
        for (int i = 0; i < 4; ++i) {
            int c = t + i * 256;
            int row = c >> 4, c4 = c & 15;
            const float4 xv = *(const float4*)(x + (size_t)(tile * 64 + row) * 768 + kb + c4 * 4);
            ushort4 o;
            o.x = f2bf(xv.x); o.y = f2bf(xv.y); o.z = f2bf(xv.z); o.w = f2bf(xv.w);
            *(ushort4*)(Alds + sw(row, c4 * 8)) = o;
        }
        // stage B x3: Wt rows (e-major, d-contiguous) -> swizzled
        for (int w3 = 0; w3 < 3; ++w3) {
            const unsigned short* src = wt + (size_t)((w3 * 12 + h) * 64) * 768 + kb;
            char* Blds = smem + 8192 * (1 + w3);
            for (int i = 0; i < 2; ++i) {
                int c = t + i * 256;
                int e = c >> 3, cb = (c & 7) * 16;
                bf16x8 bv = *(const bf16x8*)((const char*)(src + (size_t)e * 768) + cb);
                *(bf16x8*)(Blds + sw(e, cb)) = bv;
            }
        }
        __syncthreads();
        // compute: 24 MFMA / wave / k-step
        for (int kk = 0; kk < 2; ++kk) {
            bf16x8 a[2];
            for (int m = 0; m < 2; ++m)
                a[m] = *(const bf16x8*)(Alds + sw(wr * 32 + m * 16 + llo, kk * 64 + lhi * 16));
            for (int w3 = 0; w3 < 3; ++w3) {
                char* Blds = smem + 8192 * (1 + w3);
                for (int n = 0; n < 2; ++n) {
                    bf16x8 b = *(const bf16x8*)(Blds + sw(wc * 32 + n * 16 + llo, kk * 64 + lhi * 16));
                    for (int m = 0; m < 2; ++m)
                        acc[w3][m][n] = MFMA16(a[m], b, acc[w3][m][n]);
                }
            }
        }
    }
    // epilogue: C row=(lane>>4)*4+reg, col=lane&15  (m89-verified layout)
    unsigned short* outp[3] = {q, k, v};
    for (int w3 = 0; w3 < 3; ++w3)
        for (int m = 0; m < 2; ++m)
            for (int n = 0; n < 2; ++n)
                for (int r = 0; r < 4; ++r) {
                    int srow = tile * 64 + wr * 32 + m * 16 + lhi * 4 + r;
                    int b = srow >> 11, s = srow & 2047;
                    int e = wc * 32 + n * 16 + llo;
                    outp[w3][(size_t)((b * 12 + h) * 2048 + s) * 64 + e] = f2bf(acc[w3][m][n][r]);
                }
}

// ---------------------------------------------------------------------------
// Kernel 3: flash attention.  grid (32 q-tiles, 24 b*h), 256 thr = 4 waves.
// Each wave: 16 q-rows.  KBLK=64.  Causal mask on diagonal tile only.
// ---------------------------------------------------------------------------
__global__ __launch_bounds__(256) void attn(const unsigned short* __restrict__ Q,
                                            const unsigned short* __restrict__ K,
                                            const unsigned short* __restrict__ V,
                                            float* __restrict__ out) {
    __shared__ char smem[3 * 8192];          // K(8K) + V^T(8K) + P(4x2K)
    char* Klds = smem;
    char* Vlds = smem + 8192;

    const int qt = 31 - (int)blockIdx.x;     // heavy tiles dispatched first
    const int bh = (int)blockIdx.y;
    const int b = bh / 12, h = bh % 12;
    const int t = threadIdx.x, wave = t >> 6, lane = t & 63;
    const int lhi = lane >> 4, llo = lane & 15;

    const unsigned short* Qg = Q + (size_t)bh * 2048 * 64;
    const unsigned short* Kg = K + (size_t)bh * 2048 * 64;
    const unsigned short* Vg = V + (size_t)bh * 2048 * 64;
    char* Pw = smem + 16384 + wave * 2048;   // wave-private P tile [16][128B]

    // Q fragments live in registers for the whole k-loop.
    // A layout: row = lane&15, k = (lane>>4)*8 + j  (K-contiguous, 16B/lane)
    const int q0 = qt * 64 + wave * 16;
    bf16x8 qa[2];
    for (int kk = 0; kk < 2; ++kk)
        qa[kk] = *(const bf16x8*)(Qg + (size_t)(q0 + llo) * 64 + kk * 32 + lhi * 8);

    f32x4 acc[4] = {};
    float m_r[4], l_r[4];
    for (int r = 0; r < 4; ++r) { m_r[r] = -__builtin_inff(); l_r[r] = 0.f; }

    for (int kt = 0; kt <= qt; ++kt) {
        const int k0 = kt * 64;
        if (kt) __syncthreads();
        // stage K[64 kpos][64 d] bf16, swizzled
        for (int i = 0; i < 2; ++i) {
            int c = t + i * 256;
            int row = c >> 3, cb = (c & 7) * 16;
            bf16x8 kv = *(const bf16x8*)((const char*)Kg + (size_t)(k0 + row) * 128 + cb);
            *(bf16x8*)(Klds + sw(row, cb)) = kv;
        }
        // stage V transposed: Vlds[e][kpos], swizzled (PV B-operand K-contiguous)
        for (int i = 0; i < 2; ++i) {
            int c = t + i * 256;
            int row = c >> 3, e0 = (c & 7) * 8;
            bf16x8 vv = *(const bf16x8*)(Vg + (size_t)(k0 + row) * 64 + e0);
            for (int j = 0; j < 8; ++j)
                *(unsigned short*)(Vlds + sw(e0 + j, row * 2)) = (unsigned short)vv[j];
        }
        __syncthreads();

        // S = Q K^T  (B operand: col = k-position, k = d; K-contiguous rows of Klds)
        f32x4 sc[4];
        for (int n = 0; n < 4; ++n) {
            f32x4 z = {};
            for (int kk = 0; kk < 2; ++kk) {
                bf16x8 bk = *(const bf16x8*)(Klds + sw(n * 16 + llo, kk * 64 + lhi * 16));
                z = MFMA16(qa[kk], bk, z);
            }
            sc[n] = z;
        }
        // scale + causal mask (diagonal tile only)
        const bool diag = (kt == qt);
        for (int n = 0; n < 4; ++n)
            for (int r = 0; r < 4; ++r) {
                float s = sc[n][r] * 0.125f;
                if (diag) {
                    int qg = q0 + lhi * 4 + r;
                    int kg = k0 + n * 16 + llo;
                    if (kg > qg) s = -__builtin_inff();
                }
                sc[n][r] = s;
            }
        // online softmax; rows live on 16-lane groups (same lane>>4)
        float p[4][4];
        for (int r = 0; r < 4; ++r) {
            float tm = fmaxf(fmaxf(sc[0][r], sc[1][r]), fmaxf(sc[2][r], sc[3][r]));
            for (int off = 1; off < 16; off <<= 1)
                tm = fmaxf(tm, __shfl_xor(tm, off, 64));
            float nm = fmaxf(m_r[r], tm);
            float corr = __expf(m_r[r] - nm);   // first tile: exp(-inf)=0
            m_r[r] = nm;
            float ps = 0.f;
            for (int n = 0; n < 4; ++n) {
                float pv = __expf(sc[n][r] - nm);
                p[n][r] = pv;
                ps += pv;
            }
            for (int off = 1; off < 16; off <<= 1)
                ps += __shfl_xor(ps, off, 64);
            l_r[r] = l_r[r] * corr + ps;
            for (int n = 0; n < 4; ++n) acc[n][r] *= corr;
        }
        // P -> wave-private LDS (re-fragment C-layout -> A-layout)
        for (int n = 0; n < 4; ++n)
            for (int r = 0; r < 4; ++r)
                *(unsigned short*)(Pw + sw(lhi * 4 + r, (n * 16 + llo) * 2)) = f2bf(p[n][r]);
        // O += P V   (same-wave LDS RAW: compiler inserts lgkmcnt waits)
        for (int kk = 0; kk < 2; ++kk) {
            bf16x8 pa = *(const bf16x8*)(Pw + sw(llo, kk * 64 + lhi * 16));
            for (int n = 0; n < 4; ++n) {
                bf16x8 bv = *(const bf16x8*)(Vlds + sw(n * 16 + llo, kk * 64 + lhi * 16));
                acc[n] = MFMA16(pa, bv, acc[n]);
            }
        }
    }
    // epilogue: out[b][q][h*64+e] = acc / l
    for (int n = 0; n < 4; ++n)
        for (int r = 0; r < 4; ++r) {
            int qrow = q0 + lhi * 4 + r;
            int e = n * 16 + llo;
            out[(size_t)(b * 2048 + qrow) * 768 + h * 64 + e] = acc[n][r] / l_r[r];
        }
}

// ---------------------------------------------------------------------------
extern "C" void kernel_launch(void* const* d_in, const int* in_sizes, int n_in,
                              void* d_out, int out_size, void* d_ws, size_t ws_size,
                              hipStream_t stream) {
    const float* x  = (const float*)d_in[0];
    const float* Wq = (const float*)d_in[1];
    const float* Wk = (const float*)d_in[2];
    const float* Wv = (const float*)d_in[3];
    float* out = (float*)d_out;

    char* ws = (char*)d_ws;
    unsigned short* wt = (unsigned short*)(ws);                    // 3.4 MB
    unsigned short* q  = (unsigned short*)(ws + 3538944);          // 6 MB each
    unsigned short* k  = (unsigned short*)(ws + 9830400);
    unsigned short* v  = (unsigned short*)(ws + 16121856);
    // requires ws_size >= 22413312 bytes

    hipLaunchKernelGGL(prep_wt, dim3(36), dim3(256), 0, stream, Wq, Wk, Wv, wt);
    hipLaunchKernelGGL(proj_qkv, dim3(64, 12), dim3(256), 0, stream, x, wt, q, k, v);
    hipLaunchKernelGGL(attn, dim3(32, 24), dim3(256), 0, stream, q, k, v, out);
}

// Round 2
// 149.791 us; speedup vs baseline: 1.2295x; 1.2295x over previous
//
#include <hip/hip_runtime.h>
#include <hip/hip_bf16.h>

// MultiHeadAttention fused forward, MI355X/gfx950.
// B=2, S=2048, D_IN=768, H=12, D=64.  out[b,s,h*64+e] fp32.
//
// Pipeline:
//   1. prep_wt : W[h,d,e] fp32 -> Wt[w,h,e,d] bf16
//   2. proj_qkv: x @ {Wq,Wk,Wv} -> Q(prescaled by 0.125*log2e), K  [B,H,S,64]
//                and Vt [B,H,64,S] (transposed via LDS tile in epilogue)
//   3. attn    : flash attention, triple-balanced grid of 256 blocks,
//                double-buffered K/Vt staging (T14 issue-early/write-late),
//                exp2-domain online softmax.
//
// Workspace: Wt [0,3538944) | Q [3538944,9830400) | K [9830400,16121856)
//            Vt [16121856,22413312)

typedef short bf16x8 __attribute__((ext_vector_type(8)));
typedef float f32x4  __attribute__((ext_vector_type(4)));

#define MFMA16(a, b, c) __builtin_amdgcn_mfma_f32_16x16x32_bf16((a), (b), (c), 0, 0, 0)

static __device__ __forceinline__ unsigned short f2bf(float f) {
    unsigned int u = __builtin_bit_cast(unsigned int, f);
    u += 0x7fffu + ((u >> 16) & 1u);
    return (unsigned short)(u >> 16);
}

// XOR swizzle for [row][128B] LDS tiles (kills 16-way conflicts on b128 column
// slices; flips only byte bits 4..6 so 16B blocks stay contiguous).
static __device__ __forceinline__ int sw(int row, int cb) {
    return (row << 7) + (cb ^ ((row & 7) << 4));
}

// ---------------------------------------------------------------------------
// Kernel 1: W[h][d][e] fp32 -> Wt[(w*12+h)*64+e][768 d] bf16   (grid 36)
// ---------------------------------------------------------------------------
__global__ __launch_bounds__(256) void prep_wt(const float* __restrict__ Wq,
                                               const float* __restrict__ Wk,
                                               const float* __restrict__ Wv,
                                               unsigned short* __restrict__ wt) {
    __shared__ float tile[64][65];
    const int w = blockIdx.x / 12, h = blockIdx.x % 12;
    const float* W = (w == 0) ? Wq : (w == 1) ? Wk : Wv;
    const int t = threadIdx.x;
    for (int dt = 0; dt < 12; ++dt) {
        for (int i = 0; i < 4; ++i) {
            int c = t + i * 256;
            int d = c >> 4, e4 = (c & 15) * 4;
            const float4 v = *(const float4*)(W + (size_t)(h * 768 + dt * 64 + d) * 64 + e4);
            tile[d][e4 + 0] = v.x; tile[d][e4 + 1] = v.y;
            tile[d][e4 + 2] = v.z; tile[d][e4 + 3] = v.w;
        }
        __syncthreads();
        for (int i = 0; i < 4; ++i) {
            int c = t + i * 256;
            int e = c >> 4, d4 = (c & 15) * 4;
            ushort4 o;
            o.x = f2bf(tile[d4 + 0][e]); o.y = f2bf(tile[d4 + 1][e]);
            o.z = f2bf(tile[d4 + 2][e]); o.w = f2bf(tile[d4 + 3][e]);
            *(ushort4*)(wt + (size_t)((w * 12 + h) * 64 + e) * 768 + dt * 64 + d4) = o;
        }
        __syncthreads();
    }
}

// ---------------------------------------------------------------------------
// Kernel 2: QKV projection.  grid (64 m-tiles, 12 heads), 4 waves.
// Q pre-scaled by 0.125*log2(e); V written transposed to Vt[bh][e][s].
// ---------------------------------------------------------------------------
__global__ __launch_bounds__(256) void proj_qkv(const float* __restrict__ x,
                                                const unsigned short* __restrict__ wt,
                                                unsigned short* __restrict__ q,
                                                unsigned short* __restrict__ k,
                                                unsigned short* __restrict__ vtg) {
    __shared__ __align__(16) char smem[4 * 8192];
    __shared__ unsigned short vt[64][66];   // V transpose tile (pad 66: conflict-light)
    char* Alds = smem;

    const int tile = blockIdx.x;
    const int h = blockIdx.y;
    const int t = threadIdx.x;
    const int wave = t >> 6, lane = t & 63;
    const int lhi = lane >> 4, llo = lane & 15;
    const int wr = wave >> 1, wc = wave & 1;

    f32x4 acc[3][2][2] = {};

    for (int kb = 0; kb < 768; kb += 64) {
        if (kb) __syncthreads();
        for (int i = 0; i < 4; ++i) {
            int c = t + i * 256;
            int row = c >> 4, c4 = c & 15;
            const float4 xv = *(const float4*)(x + (size_t)(tile * 64 + row) * 768 + kb + c4 * 4);
            ushort4 o;
            o.x = f2bf(xv.x); o.y = f2bf(xv.y); o.z = f2bf(xv.z); o.w = f2bf(xv.w);
            *(ushort4*)(Alds + sw(row, c4 * 8)) = o;
        }
        for (int w3 = 0; w3 < 3; ++w3) {
            const unsigned short* src = wt + (size_t)((w3 * 12 + h) * 64) * 768 + kb;
            char* Blds = smem + 8192 * (1 + w3);
            for (int i = 0; i < 2; ++i) {
                int c = t + i * 256;
                int e = c >> 3, cb = (c & 7) * 16;
                bf16x8 bv = *(const bf16x8*)((const char*)(src + (size_t)e * 768) + cb);
                *(bf16x8*)(Blds + sw(e, cb)) = bv;
            }
        }
        __syncthreads();
        for (int kk = 0; kk < 2; ++kk) {
            bf16x8 a[2];
            for (int m = 0; m < 2; ++m)
                a[m] = *(const bf16x8*)(Alds + sw(wr * 32 + m * 16 + llo, kk * 64 + lhi * 16));
            for (int w3 = 0; w3 < 3; ++w3) {
                char* Blds = smem + 8192 * (1 + w3);
                for (int n = 0; n < 2; ++n) {
                    bf16x8 b = *(const bf16x8*)(Blds + sw(wc * 32 + n * 16 + llo, kk * 64 + lhi * 16));
                    for (int m = 0; m < 2; ++m)
                        acc[w3][m][n] = MFMA16(a[m], b, acc[w3][m][n]);
                }
            }
        }
    }

    // epilogue: C row=(lane>>4)*4+reg, col=lane&15
    const float SCALE_Q = 0.18033688011112042f;  // 0.125 * log2(e)
    unsigned short* dst01[2] = {q, k};
    #pragma unroll
    for (int w3 = 0; w3 < 2; ++w3)
        for (int m = 0; m < 2; ++m)
            for (int n = 0; n < 2; ++n)
                for (int r = 0; r < 4; ++r) {
                    int srow = tile * 64 + wr * 32 + m * 16 + lhi * 4 + r;
                    int b = srow >> 11, s = srow & 2047;
                    int e = wc * 32 + n * 16 + llo;
                    float val = acc[w3][m][n][r] * (w3 == 0 ? SCALE_Q : 1.0f);
                    dst01[w3][(size_t)((b * 12 + h) * 2048 + s) * 64 + e] = f2bf(val);
                }
    // V: transpose through LDS, write Vt[bh][e][s] coalesced
    __syncthreads();
    for (int m = 0; m < 2; ++m)
        for (int n = 0; n < 2; ++n)
            for (int r = 0; r < 4; ++r)
                vt[wr * 32 + m * 16 + lhi * 4 + r][wc * 32 + n * 16 + llo] =
                    f2bf(acc[2][m][n][r]);
    __syncthreads();
    {
        const int e = t >> 2, j = t & 3;
        const int b = tile >> 5;
        const int sbase = (tile & 31) * 64;
        unsigned short* dv = vtg + ((size_t)((b * 12 + h) * 64 + e)) * 2048 + sbase + j * 16;
        #pragma unroll
        for (int half = 0; half < 2; ++half) {
            bf16x8 o;
            #pragma unroll
            for (int mm = 0; mm < 8; ++mm)
                o[mm] = (short)vt[j * 16 + half * 8 + mm][e];
            *(bf16x8*)(dv + half * 8) = o;
        }
    }
}

// ---------------------------------------------------------------------------
// Kernel 3: flash attention.  grid = 256 blocks, each a balanced TRIPLE of
// q-tiles: (t, (t+16)%32, t<16?30-2t:63-2t) -> 49/50 k-iters per block.
// 4 waves x 16 q-rows, KBLK=64, double-buffered K/Vt, one barrier per iter.
// ---------------------------------------------------------------------------
__global__ __launch_bounds__(256) void attn(const unsigned short* __restrict__ Q,
                                            const unsigned short* __restrict__ K,
                                            const unsigned short* __restrict__ Vt,
                                            float* __restrict__ out) {
    __shared__ __align__(16) char smem[40960];  // K dbuf 16K | Vt dbuf 16K | P 8K
    const int t = threadIdx.x, wave = t >> 6, lane = t & 63;
    const int lhi = lane >> 4, llo = lane & 15;
    const int sr0 = t >> 3, scb = (t & 7) * 16;  // staging coords
    const int tt = blockIdx.x & 31, grp = blockIdx.x >> 5;
    char* Pw = smem + 32768 + wave * 2048;

    for (int e3 = 0; e3 < 3; ++e3) {
        const int qt = (e3 == 0) ? tt
                     : (e3 == 1) ? ((tt + 16) & 31)
                                 : ((tt < 16) ? 30 - 2 * tt : 63 - 2 * tt);
        const int bh = grp * 3 + e3;
        const unsigned short* Qg = Q + (size_t)bh * 2048 * 64;
        const char* Kg = (const char*)(K + (size_t)bh * 2048 * 64);
        const char* Vg = (const char*)(Vt + (size_t)bh * 64 * 2048);

        const int q0 = qt * 64 + wave * 16;
        bf16x8 qa[2];
        #pragma unroll
        for (int kk = 0; kk < 2; ++kk)
            qa[kk] = *(const bf16x8*)(Qg + (size_t)(q0 + llo) * 64 + kk * 32 + lhi * 8);

        f32x4 acc[4] = {};
        float m_r[4], l_r[4];
        #pragma unroll
        for (int r = 0; r < 4; ++r) { m_r[r] = -1e30f; l_r[r] = 0.f; }

        bf16x8 kreg[2], vreg[2];
        #pragma unroll
        for (int i = 0; i < 2; ++i) {   // prefetch tile 0
            int row = sr0 + i * 32;
            kreg[i] = *(const bf16x8*)(Kg + (size_t)row * 128 + scb);
            vreg[i] = *(const bf16x8*)(Vg + (size_t)row * 4096 + scb);
        }
        #pragma unroll
        for (int i = 0; i < 2; ++i) {   // write buf 0
            int row = sr0 + i * 32;
            *(bf16x8*)(smem + sw(row, scb)) = kreg[i];
            *(bf16x8*)(smem + 16384 + sw(row, scb)) = vreg[i];
        }
        __syncthreads();

        int cur = 0;
        for (int kt = 0; kt <= qt; ++kt) {
            if (kt < qt) {  // issue loads for kt+1 early (hide under compute)
                const int k0 = (kt + 1) * 64;
                #pragma unroll
                for (int i = 0; i < 2; ++i) {
                    int row = sr0 + i * 32;
                    kreg[i] = *(const bf16x8*)(Kg + (size_t)(k0 + row) * 128 + scb);
                    vreg[i] = *(const bf16x8*)(Vg + (size_t)row * 4096 + k0 * 2 + scb);
                }
            }
            char* Kb = smem + cur * 8192;
            char* Vb = smem + 16384 + cur * 8192;

            // S = Q K^T   (Q pre-scaled; scores already in exp2 domain)
            f32x4 sc[4];
            #pragma unroll
            for (int n = 0; n < 4; ++n) {
                f32x4 z = {};
                #pragma unroll
                for (int kk = 0; kk < 2; ++kk) {
                    bf16x8 bk = *(const bf16x8*)(Kb + sw(n * 16 + llo, kk * 64 + lhi * 16));
                    z = MFMA16(qa[kk], bk, z);
                }
                sc[n] = z;
            }
            if (kt == qt) {   // causal mask, diagonal tile only
                #pragma unroll
                for (int n = 0; n < 4; ++n)
                    #pragma unroll
                    for (int r = 0; r < 4; ++r)
                        if (kt * 64 + n * 16 + llo > q0 + lhi * 4 + r) sc[n][r] = -1e30f;
            }
            // online softmax (exp2 domain); rows on 16-lane groups
            float p[4][4];
            #pragma unroll
            for (int r = 0; r < 4; ++r) {
                float tm = fmaxf(fmaxf(sc[0][r], sc[1][r]), fmaxf(sc[2][r], sc[3][r]));
                #pragma unroll
                for (int off = 1; off < 16; off <<= 1)
                    tm = fmaxf(tm, __shfl_xor(tm, off, 64));
                float nm = fmaxf(m_r[r], tm);
                float corr = exp2f(m_r[r] - nm);
                m_r[r] = nm;
                float ps = 0.f;
                #pragma unroll
                for (int n = 0; n < 4; ++n) { p[n][r] = exp2f(sc[n][r] - nm); ps += p[n][r]; }
                #pragma unroll
                for (int off = 1; off < 16; off <<= 1)
                    ps += __shfl_xor(ps, off, 64);
                l_r[r] = l_r[r] * corr + ps;
                #pragma unroll
                for (int n = 0; n < 4; ++n) acc[n][r] *= corr;
            }
            // P -> wave-private LDS, lhi-staggered column order (bank-even)
            #pragma unroll
            for (int n0 = 0; n0 < 4; ++n0) {
                int n = (n0 + lhi) & 3;
                #pragma unroll
                for (int r = 0; r < 4; ++r)
                    *(unsigned short*)(Pw + sw(lhi * 4 + r, (n * 16 + llo) * 2)) = f2bf(p[n][r]);
            }
            // O += P V
            #pragma unroll
            for (int kk = 0; kk < 2; ++kk) {
                bf16x8 pa = *(const bf16x8*)(Pw + sw(llo, kk * 64 + lhi * 16));
                #pragma unroll
                for (int n = 0; n < 4; ++n) {
                    bf16x8 bv = *(const bf16x8*)(Vb + sw(n * 16 + llo, kk * 64 + lhi * 16));
                    acc[n] = MFMA16(pa, bv, acc[n]);
                }
            }
            if (kt < qt) {  // write next tile into the other buffer
                char* Kw = smem + (cur ^ 1) * 8192;
                char* Vw = smem + 16384 + (cur ^ 1) * 8192;
                #pragma unroll
                for (int i = 0; i < 2; ++i) {
                    int row = sr0 + i * 32;
                    *(bf16x8*)(Kw + sw(row, scb)) = kreg[i];
                    *(bf16x8*)(Vw + sw(row, scb)) = vreg[i];
                }
            }
            __syncthreads();
            cur ^= 1;
        }
        // epilogue
        const int b = bh / 12, h = bh - b * 12;
        #pragma unroll
        for (int n = 0; n < 4; ++n)
            #pragma unroll
            for (int r = 0; r < 4; ++r)
                out[(size_t)(b * 2048 + q0 + lhi * 4 + r) * 768 + h * 64 + n * 16 + llo] =
                    acc[n][r] / l_r[r];
    }
}

// ---------------------------------------------------------------------------
extern "C" void kernel_launch(void* const* d_in, const int* in_sizes, int n_in,
                              void* d_out, int out_size, void* d_ws, size_t ws_size,
                              hipStream_t stream) {
    const float* x  = (const float*)d_in[0];
    const float* Wq = (const float*)d_in[1];
    const float* Wk = (const float*)d_in[2];
    const float* Wv = (const float*)d_in[3];
    float* out = (float*)d_out;

    char* ws = (char*)d_ws;
    unsigned short* wt = (unsigned short*)(ws);
    unsigned short* q  = (unsigned short*)(ws + 3538944);
    unsigned short* k  = (unsigned short*)(ws + 9830400);
    unsigned short* vt = (unsigned short*)(ws + 16121856);
    // requires ws_size >= 22413312 bytes

    hipLaunchKernelGGL(prep_wt, dim3(36), dim3(256), 0, stream, Wq, Wk, Wv, wt);
    hipLaunchKernelGGL(proj_qkv, dim3(64, 12), dim3(256), 0, stream, x, wt, q, k, vt);
    hipLaunchKernelGGL(attn, dim3(256), dim3(256), 0, stream, q, k, vt, out);
}

// Round 3
// 87.269 us; speedup vs baseline: 2.1103x; 1.7164x over previous
//
#include <hip/hip_runtime.h>
#include <hip/hip_bf16.h>

// MultiHeadAttention fused forward, MI355X/gfx950.
// B=2, S=2048, D_IN=768, H=12, D=64.  out[b,s,h*64+e] fp32.
//
// Pipeline:
//   1. prep_wt : W[h,d,e] fp32 -> Wt[w,h,e,d] bf16
//   2. proj_qkv: x @ {Wq,Wk,Wv} -> Q(prescaled by 0.125*log2e), K  [B,H,S,64]
//                and Vt [B,H,64,S] (transposed via LDS tile in epilogue)
//   3. attn    : flash attention, 768 blocks (3/CU, balanced qt triples per CU),
//                SWAPPED QK^T (S^T = K*Q^T) so softmax rows are lane-local,
//                cvt_pk P packing, double-buffered K/Vt, exp2-domain softmax.
//
// Workspace: Wt [0,3538944) | Q [3538944,9830400) | K [9830400,16121856)
//            Vt [16121856,22413312)

typedef short bf16x8 __attribute__((ext_vector_type(8)));
typedef float f32x4  __attribute__((ext_vector_type(4)));

#define MFMA16(a, b, c) __builtin_amdgcn_mfma_f32_16x16x32_bf16((a), (b), (c), 0, 0, 0)

static __device__ __forceinline__ unsigned short f2bf(float f) {
    unsigned int u = __builtin_bit_cast(unsigned int, f);
    u += 0x7fffu + ((u >> 16) & 1u);
    return (unsigned short)(u >> 16);
}

// XOR swizzle for [row][128B] LDS tiles (kills 16-way conflicts on b128 column
// slices; flips only byte bits 4..6 so 16B blocks stay contiguous, 8B aligned ok).
static __device__ __forceinline__ int sw(int row, int cb) {
    return (row << 7) + (cb ^ ((row & 7) << 4));
}

// ---------------------------------------------------------------------------
// Kernel 1: W[h][d][e] fp32 -> Wt[(w*12+h)*64+e][768 d] bf16   (grid 36)
// ---------------------------------------------------------------------------
__global__ __launch_bounds__(256) void prep_wt(const float* __restrict__ Wq,
                                               const float* __restrict__ Wk,
                                               const float* __restrict__ Wv,
                                               unsigned short* __restrict__ wt) {
    __shared__ float tile[64][65];
    const int w = blockIdx.x / 12, h = blockIdx.x % 12;
    const float* W = (w == 0) ? Wq : (w == 1) ? Wk : Wv;
    const int t = threadIdx.x;
    for (int dt = 0; dt < 12; ++dt) {
        for (int i = 0; i < 4; ++i) {
            int c = t + i * 256;
            int d = c >> 4, e4 = (c & 15) * 4;
            const float4 v = *(const float4*)(W + (size_t)(h * 768 + dt * 64 + d) * 64 + e4);
            tile[d][e4 + 0] = v.x; tile[d][e4 + 1] = v.y;
            tile[d][e4 + 2] = v.z; tile[d][e4 + 3] = v.w;
        }
        __syncthreads();
        for (int i = 0; i < 4; ++i) {
            int c = t + i * 256;
            int e = c >> 4, d4 = (c & 15) * 4;
            ushort4 o;
            o.x = f2bf(tile[d4 + 0][e]); o.y = f2bf(tile[d4 + 1][e]);
            o.z = f2bf(tile[d4 + 2][e]); o.w = f2bf(tile[d4 + 3][e]);
            *(ushort4*)(wt + (size_t)((w * 12 + h) * 64 + e) * 768 + dt * 64 + d4) = o;
        }
        __syncthreads();
    }
}

// ---------------------------------------------------------------------------
// Kernel 2: QKV projection.  grid (64 m-tiles, 12 heads), 4 waves.
// Q pre-scaled by 0.125*log2(e); V written transposed to Vt[bh][e][s].
// ---------------------------------------------------------------------------
__global__ __launch_bounds__(256) void proj_qkv(const float* __restrict__ x,
                                                const unsigned short* __restrict__ wt,
                                                unsigned short* __restrict__ q,
                                                unsigned short* __restrict__ k,
                                                unsigned short* __restrict__ vtg) {
    __shared__ __align__(16) char smem[4 * 8192];
    __shared__ unsigned short vt[64][66];
    char* Alds = smem;

    const int tile = blockIdx.x;
    const int h = blockIdx.y;
    const int t = threadIdx.x;
    const int wave = t >> 6, lane = t & 63;
    const int lhi = lane >> 4, llo = lane & 15;
    const int wr = wave >> 1, wc = wave & 1;

    f32x4 acc[3][2][2] = {};

    for (int kb = 0; kb < 768; kb += 64) {
        if (kb) __syncthreads();
        for (int i = 0; i < 4; ++i) {
            int c = t + i * 256;
            int row = c >> 4, c4 = c & 15;
            const float4 xv = *(const float4*)(x + (size_t)(tile * 64 + row) * 768 + kb + c4 * 4);
            ushort4 o;
            o.x = f2bf(xv.x); o.y = f2bf(xv.y); o.z = f2bf(xv.z); o.w = f2bf(xv.w);
            *(ushort4*)(Alds + sw(row, c4 * 8)) = o;
        }
        for (int w3 = 0; w3 < 3; ++w3) {
            const unsigned short* src = wt + (size_t)((w3 * 12 + h) * 64) * 768 + kb;
            char* Blds = smem + 8192 * (1 + w3);
            for (int i = 0; i < 2; ++i) {
                int c = t + i * 256;
                int e = c >> 3, cb = (c & 7) * 16;
                bf16x8 bv = *(const bf16x8*)((const char*)(src + (size_t)e * 768) + cb);
                *(bf16x8*)(Blds + sw(e, cb)) = bv;
            }
        }
        __syncthreads();
        for (int kk = 0; kk < 2; ++kk) {
            bf16x8 a[2];
            for (int m = 0; m < 2; ++m)
                a[m] = *(const bf16x8*)(Alds + sw(wr * 32 + m * 16 + llo, kk * 64 + lhi * 16));
            for (int w3 = 0; w3 < 3; ++w3) {
                char* Blds = smem + 8192 * (1 + w3);
                for (int n = 0; n < 2; ++n) {
                    bf16x8 b = *(const bf16x8*)(Blds + sw(wc * 32 + n * 16 + llo, kk * 64 + lhi * 16));
                    for (int m = 0; m < 2; ++m)
                        acc[w3][m][n] = MFMA16(a[m], b, acc[w3][m][n]);
                }
            }
        }
    }

    const float SCALE_Q = 0.18033688011112042f;  // 0.125 * log2(e)
    unsigned short* dst01[2] = {q, k};
    #pragma unroll
    for (int w3 = 0; w3 < 2; ++w3)
        for (int m = 0; m < 2; ++m)
            for (int n = 0; n < 2; ++n)
                for (int r = 0; r < 4; ++r) {
                    int srow = tile * 64 + wr * 32 + m * 16 + lhi * 4 + r;
                    int b = srow >> 11, s = srow & 2047;
                    int e = wc * 32 + n * 16 + llo;
                    float val = acc[w3][m][n][r] * (w3 == 0 ? SCALE_Q : 1.0f);
                    dst01[w3][(size_t)((b * 12 + h) * 2048 + s) * 64 + e] = f2bf(val);
                }
    __syncthreads();
    for (int m = 0; m < 2; ++m)
        for (int n = 0; n < 2; ++n)
            for (int r = 0; r < 4; ++r)
                vt[wr * 32 + m * 16 + lhi * 4 + r][wc * 32 + n * 16 + llo] =
                    f2bf(acc[2][m][n][r]);
    __syncthreads();
    {
        const int e = t >> 2, j = t & 3;
        const int b = tile >> 5;
        const int sbase = (tile & 31) * 64;
        unsigned short* dv = vtg + ((size_t)((b * 12 + h) * 64 + e)) * 2048 + sbase + j * 16;
        #pragma unroll
        for (int half = 0; half < 2; ++half) {
            bf16x8 o;
            #pragma unroll
            for (int mm = 0; mm < 8; ++mm)
                o[mm] = (short)vt[j * 16 + half * 8 + mm][e];
            *(bf16x8*)(dv + half * 8) = o;
        }
    }
}

// ---------------------------------------------------------------------------
// Kernel 3: flash attention.  grid = 768 blocks (3/CU), block = one (bh, qt);
// blocks c, c+256, c+512 form a balanced qt triple on the same CU.
// SWAPPED QK^T: sc = K*Q^T, so each lane owns one q-row (q = llo) -> softmax
// max = in-lane tree + 2 shfl; sum deferred per-lane; P packed with cvt_pk.
// PV: O^T = mfma(V^T-frag, P-frag).  Double-buffered K/Vt staging.
// ---------------------------------------------------------------------------
__global__ __launch_bounds__(256) void attn(const unsigned short* __restrict__ Q,
                                            const unsigned short* __restrict__ K,
                                            const unsigned short* __restrict__ Vt,
                                            float* __restrict__ out) {
    __shared__ __align__(16) char smem[40960];  // K dbuf 16K | Vt dbuf 16K | P 4x2K
    const int t = threadIdx.x, wave = t >> 6, lane = t & 63;
    const int lhi = lane >> 4, llo = lane & 15;
    const int sr0 = t >> 3, scb = (t & 7) * 16;
    const int bid = blockIdx.x;
    const int tt = bid & 31, grp = (bid >> 5) & 7, e3 = bid >> 8;
    const int qt = (e3 == 0) ? tt
                 : (e3 == 1) ? ((tt + 16) & 31)
                             : ((tt < 16) ? 30 - 2 * tt : 63 - 2 * tt);
    const int bh = grp * 3 + e3;
    const unsigned short* Qg = Q + (size_t)bh * 2048 * 64;
    const char* Kg = (const char*)(K + (size_t)bh * 2048 * 64);
    const char* Vg = (const char*)(Vt + (size_t)bh * 64 * 2048);
    char* Pw = smem + 32768 + wave * 2048;   // wave-private P tile [16 q][128B k]

    const int q0 = qt * 64 + wave * 16;      // this wave's q-block; lane q = q0+llo
    bf16x8 qa[2];
    #pragma unroll
    for (int kk = 0; kk < 2; ++kk)
        qa[kk] = *(const bf16x8*)(Qg + (size_t)(q0 + llo) * 64 + kk * 32 + lhi * 8);

    f32x4 acc[4] = {};                       // O^T: acc[n][r] -> e = n*16+lhi*4+r, q = llo
    float m_r = -1e30f, l_r = 0.f;

    bf16x8 kreg[2], vreg[2];
    #pragma unroll
    for (int i = 0; i < 2; ++i) {            // prefetch tile 0
        int row = sr0 + i * 32;
        kreg[i] = *(const bf16x8*)(Kg + (size_t)row * 128 + scb);
        vreg[i] = *(const bf16x8*)(Vg + (size_t)row * 4096 + scb);
    }
    #pragma unroll
    for (int i = 0; i < 2; ++i) {
        int row = sr0 + i * 32;
        *(bf16x8*)(smem + sw(row, scb)) = kreg[i];
        *(bf16x8*)(smem + 16384 + sw(row, scb)) = vreg[i];
    }
    __syncthreads();

    int cur = 0;
    for (int kt = 0; kt <= qt; ++kt) {
        if (kt < qt) {  // issue next-tile loads early (hide under compute)
            const int k0 = (kt + 1) * 64;
            #pragma unroll
            for (int i = 0; i < 2; ++i) {
                int row = sr0 + i * 32;
                kreg[i] = *(const bf16x8*)(Kg + (size_t)(k0 + row) * 128 + scb);
                vreg[i] = *(const bf16x8*)(Vg + (size_t)row * 4096 + k0 * 2 + scb);
            }
        }
        char* Kb = smem + cur * 8192;
        char* Vb = smem + 16384 + cur * 8192;

        // S^T = K Q^T: sc[n] rows = k-pos (n*16+lhi*4+r), col = q (llo)
        f32x4 sc[4];
        __builtin_amdgcn_s_setprio(1);
        #pragma unroll
        for (int n = 0; n < 4; ++n) {
            f32x4 z = {};
            #pragma unroll
            for (int kk = 0; kk < 2; ++kk) {
                bf16x8 bk = *(const bf16x8*)(Kb + sw(n * 16 + llo, kk * 64 + lhi * 16));
                z = MFMA16(bk, qa[kk], z);   // A = K rows, B = Q rows as cols
            }
            sc[n] = z;
        }
        __builtin_amdgcn_s_setprio(0);
        if (kt == qt) {   // causal mask, diagonal tile only
            #pragma unroll
            for (int n = 0; n < 4; ++n)
                #pragma unroll
                for (int r = 0; r < 4; ++r)
                    if (kt * 64 + n * 16 + lhi * 4 + r > q0 + llo) sc[n][r] = -1e30f;
        }
        // row max: in-lane tree over 16 + cross-lhi (2 shfl)
        float tm = fmaxf(fmaxf(fmaxf(sc[0][0], sc[0][1]), fmaxf(sc[0][2], sc[0][3])),
                         fmaxf(fmaxf(sc[1][0], sc[1][1]), fmaxf(sc[1][2], sc[1][3])));
        float tm2 = fmaxf(fmaxf(fmaxf(sc[2][0], sc[2][1]), fmaxf(sc[2][2], sc[2][3])),
                          fmaxf(fmaxf(sc[3][0], sc[3][1]), fmaxf(sc[3][2], sc[3][3])));
        tm = fmaxf(tm, tm2);
        tm = fmaxf(tm, __shfl_xor(tm, 16, 64));
        tm = fmaxf(tm, __shfl_xor(tm, 32, 64));
        float nm = fmaxf(m_r, tm);
        float corr = exp2f(m_r - nm);
        m_r = nm;
        // P = exp2(sc - nm); pack pairs with cvt_pk, 4x ds_write_b64
        float ps = 0.f;
        #pragma unroll
        for (int n = 0; n < 4; ++n) {
            float p0 = exp2f(sc[n][0] - nm), p1 = exp2f(sc[n][1] - nm);
            float p2 = exp2f(sc[n][2] - nm), p3 = exp2f(sc[n][3] - nm);
            ps += (p0 + p1) + (p2 + p3);
            unsigned int w0, w1;
            asm("v_cvt_pk_bf16_f32 %0, %1, %2" : "=v"(w0) : "v"(p0), "v"(p1));
            asm("v_cvt_pk_bf16_f32 %0, %1, %2" : "=v"(w1) : "v"(p2), "v"(p3));
            uint2 pk; pk.x = w0; pk.y = w1;
            *(uint2*)(Pw + sw(llo, n * 32 + lhi * 8)) = pk;  // P[q=llo][k-run]
        }
        l_r = l_r * corr + ps;   // cross-lhi sum deferred to epilogue
        #pragma unroll
        for (int n = 0; n < 4; ++n)
            #pragma unroll
            for (int r = 0; r < 4; ++r) acc[n][r] *= corr;
        // O^T += V^T P^T
        __builtin_amdgcn_s_setprio(1);
        #pragma unroll
        for (int kk = 0; kk < 2; ++kk) {
            bf16x8 pa = *(const bf16x8*)(Pw + sw(llo, kk * 64 + lhi * 16));
            #pragma unroll
            for (int n = 0; n < 4; ++n) {
                bf16x8 bv = *(const bf16x8*)(Vb + sw(n * 16 + llo, kk * 64 + lhi * 16));
                acc[n] = MFMA16(bv, pa, acc[n]);  // A = V^T rows (e), B = P cols (q)
            }
        }
        __builtin_amdgcn_s_setprio(0);
        if (kt < qt) {  // write next tile into the other buffer
            char* Kw = smem + (cur ^ 1) * 8192;
            char* Vw = smem + 16384 + (cur ^ 1) * 8192;
            #pragma unroll
            for (int i = 0; i < 2; ++i) {
                int row = sr0 + i * 32;
                *(bf16x8*)(Kw + sw(row, scb)) = kreg[i];
                *(bf16x8*)(Vw + sw(row, scb)) = vreg[i];
            }
        }
        __syncthreads();
        cur ^= 1;
    }
    // finish the deferred l reduction (4 lhi partials of row q=llo)
    l_r += __shfl_xor(l_r, 16, 64);
    l_r += __shfl_xor(l_r, 32, 64);
    const float inv = 1.0f / l_r;
    const int b = bh / 12, h = bh - b * 12;
    #pragma unroll
    for (int n = 0; n < 4; ++n) {
        float4 o;
        o.x = acc[n][0] * inv; o.y = acc[n][1] * inv;
        o.z = acc[n][2] * inv; o.w = acc[n][3] * inv;
        *(float4*)(out + (size_t)(b * 2048 + q0 + llo) * 768 + h * 64 + n * 16 + lhi * 4) = o;
    }
}

// ---------------------------------------------------------------------------
extern "C" void kernel_launch(void* const* d_in, const int* in_sizes, int n_in,
                              void* d_out, int out_size, void* d_ws, size_t ws_size,
                              hipStream_t stream) {
    const float* x  = (const float*)d_in[0];
    const float* Wq = (const float*)d_in[1];
    const float* Wk = (const float*)d_in[2];
    const float* Wv = (const float*)d_in[3];
    float* out = (float*)d_out;

    char* ws = (char*)d_ws;
    unsigned short* wt = (unsigned short*)(ws);
    unsigned short* q  = (unsigned short*)(ws + 3538944);
    unsigned short* k  = (unsigned short*)(ws + 9830400);
    unsigned short* vt = (unsigned short*)(ws + 16121856);
    // requires ws_size >= 22413312 bytes

    hipLaunchKernelGGL(prep_wt, dim3(36), dim3(256), 0, stream, Wq, Wk, Wv, wt);
    hipLaunchKernelGGL(proj_qkv, dim3(64, 12), dim3(256), 0, stream, x, wt, q, k, vt);
    hipLaunchKernelGGL(attn, dim3(768), dim3(256), 0, stream, q, k, vt, out);
}

// Round 4
// 86.022 us; speedup vs baseline: 2.1409x; 1.0145x over previous
//
#include <hip/hip_runtime.h>
#include <hip/hip_bf16.h>

// MultiHeadAttention fused forward, MI355X/gfx950.
// B=2, S=2048, D_IN=768, H=12, D=64.  out[b,s,h*64+e] fp32.
//
// Pipeline:
//   1. prep_wt : W[h,d,e] fp32 -> Wt[w,h,e,d] bf16
//   2. proj_qkv: x @ {Wq,Wk,Wv} -> Q(prescaled by 0.125*log2e), K  [B,H,S,64]
//                and Vt [B,H,64,S] (transposed via LDS tile in epilogue)
//   3. attn    : flash attention, 768 blocks (3/CU, balanced qt triples),
//                swapped QK^T (lane-local softmax rows), IN-REGISTER PV via
//                mfma 16x16x16 (P never touches LDS), defer-max rescale.
//
// Workspace: Wt [0,3538944) | Q [3538944,9830400) | K [9830400,16121856)
//            Vt [16121856,22413312)

typedef short bf16x8 __attribute__((ext_vector_type(8)));
typedef short bf16x4 __attribute__((ext_vector_type(4)));
typedef float f32x4  __attribute__((ext_vector_type(4)));

#define MFMA16(a, b, c)  __builtin_amdgcn_mfma_f32_16x16x32_bf16((a), (b), (c), 0, 0, 0)
#define MFMAK16(a, b, c) __builtin_amdgcn_mfma_f32_16x16x16bf16_1k((a), (b), (c), 0, 0, 0)

static __device__ __forceinline__ unsigned short f2bf(float f) {
    unsigned int u = __builtin_bit_cast(unsigned int, f);
    u += 0x7fffu + ((u >> 16) & 1u);
    return (unsigned short)(u >> 16);
}

// XOR swizzle for [row][128B] LDS tiles (kills 16-way conflicts on b128 column
// slices; flips only byte bits 4..6 so 16B blocks stay contiguous, 8B-ops stay aligned).
static __device__ __forceinline__ int sw(int row, int cb) {
    return (row << 7) + (cb ^ ((row & 7) << 4));
}

// ---------------------------------------------------------------------------
// Kernel 1: W[h][d][e] fp32 -> Wt[(w*12+h)*64+e][768 d] bf16   (grid 36)
// ---------------------------------------------------------------------------
__global__ __launch_bounds__(256) void prep_wt(const float* __restrict__ Wq,
                                               const float* __restrict__ Wk,
                                               const float* __restrict__ Wv,
                                               unsigned short* __restrict__ wt) {
    __shared__ float tile[64][65];
    const int w = blockIdx.x / 12, h = blockIdx.x % 12;
    const float* W = (w == 0) ? Wq : (w == 1) ? Wk : Wv;
    const int t = threadIdx.x;
    for (int dt = 0; dt < 12; ++dt) {
        for (int i = 0; i < 4; ++i) {
            int c = t + i * 256;
            int d = c >> 4, e4 = (c & 15) * 4;
            const float4 v = *(const float4*)(W + (size_t)(h * 768 + dt * 64 + d) * 64 + e4);
            tile[d][e4 + 0] = v.x; tile[d][e4 + 1] = v.y;
            tile[d][e4 + 2] = v.z; tile[d][e4 + 3] = v.w;
        }
        __syncthreads();
        for (int i = 0; i < 4; ++i) {
            int c = t + i * 256;
            int e = c >> 4, d4 = (c & 15) * 4;
            ushort4 o;
            o.x = f2bf(tile[d4 + 0][e]); o.y = f2bf(tile[d4 + 1][e]);
            o.z = f2bf(tile[d4 + 2][e]); o.w = f2bf(tile[d4 + 3][e]);
            *(ushort4*)(wt + (size_t)((w * 12 + h) * 64 + e) * 768 + dt * 64 + d4) = o;
        }
        __syncthreads();
    }
}

// ---------------------------------------------------------------------------
// Kernel 2: QKV projection.  grid (64 m-tiles, 12 heads), 4 waves.
// Q pre-scaled by 0.125*log2(e); V written transposed to Vt[bh][e][s].
// ---------------------------------------------------------------------------
__global__ __launch_bounds__(256) void proj_qkv(const float* __restrict__ x,
                                                const unsigned short* __restrict__ wt,
                                                unsigned short* __restrict__ q,
                                                unsigned short* __restrict__ k,
                                                unsigned short* __restrict__ vtg) {
    __shared__ __align__(16) char smem[4 * 8192];
    __shared__ unsigned short vt[64][66];
    char* Alds = smem;

    const int tile = blockIdx.x;
    const int h = blockIdx.y;
    const int t = threadIdx.x;
    const int wave = t >> 6, lane = t & 63;
    const int lhi = lane >> 4, llo = lane & 15;
    const int wr = wave >> 1, wc = wave & 1;

    f32x4 acc[3][2][2] = {};

    for (int kb = 0; kb < 768; kb += 64) {
        if (kb) __syncthreads();
        for (int i = 0; i < 4; ++i) {
            int c = t + i * 256;
            int row = c >> 4, c4 = c & 15;
            const float4 xv = *(const float4*)(x + (size_t)(tile * 64 + row) * 768 + kb + c4 * 4);
            ushort4 o;
            o.x = f2bf(xv.x); o.y = f2bf(xv.y); o.z = f2bf(xv.z); o.w = f2bf(xv.w);
            *(ushort4*)(Alds + sw(row, c4 * 8)) = o;
        }
        for (int w3 = 0; w3 < 3; ++w3) {
            const unsigned short* src = wt + (size_t)((w3 * 12 + h) * 64) * 768 + kb;
            char* Blds = smem + 8192 * (1 + w3);
            for (int i = 0; i < 2; ++i) {
                int c = t + i * 256;
                int e = c >> 3, cb = (c & 7) * 16;
                bf16x8 bv = *(const bf16x8*)((const char*)(src + (size_t)e * 768) + cb);
                *(bf16x8*)(Blds + sw(e, cb)) = bv;
            }
        }
        __syncthreads();
        for (int kk = 0; kk < 2; ++kk) {
            bf16x8 a[2];
            for (int m = 0; m < 2; ++m)
                a[m] = *(const bf16x8*)(Alds + sw(wr * 32 + m * 16 + llo, kk * 64 + lhi * 16));
            for (int w3 = 0; w3 < 3; ++w3) {
                char* Blds = smem + 8192 * (1 + w3);
                for (int n = 0; n < 2; ++n) {
                    bf16x8 b = *(const bf16x8*)(Blds + sw(wc * 32 + n * 16 + llo, kk * 64 + lhi * 16));
                    for (int m = 0; m < 2; ++m)
                        acc[w3][m][n] = MFMA16(a[m], b, acc[w3][m][n]);
                }
            }
        }
    }

    const float SCALE_Q = 0.18033688011112042f;  // 0.125 * log2(e)
    unsigned short* dst01[2] = {q, k};
    #pragma unroll
    for (int w3 = 0; w3 < 2; ++w3)
        for (int m = 0; m < 2; ++m)
            for (int n = 0; n < 2; ++n)
                for (int r = 0; r < 4; ++r) {
                    int srow = tile * 64 + wr * 32 + m * 16 + lhi * 4 + r;
                    int b = srow >> 11, s = srow & 2047;
                    int e = wc * 32 + n * 16 + llo;
                    float val = acc[w3][m][n][r] * (w3 == 0 ? SCALE_Q : 1.0f);
                    dst01[w3][(size_t)((b * 12 + h) * 2048 + s) * 64 + e] = f2bf(val);
                }
    __syncthreads();
    for (int m = 0; m < 2; ++m)
        for (int n = 0; n < 2; ++n)
            for (int r = 0; r < 4; ++r)
                vt[wr * 32 + m * 16 + lhi * 4 + r][wc * 32 + n * 16 + llo] =
                    f2bf(acc[2][m][n][r]);
    __syncthreads();
    {
        const int e = t >> 2, j = t & 3;
        const int b = tile >> 5;
        const int sbase = (tile & 31) * 64;
        unsigned short* dv = vtg + ((size_t)((b * 12 + h) * 64 + e)) * 2048 + sbase + j * 16;
        #pragma unroll
        for (int half = 0; half < 2; ++half) {
            bf16x8 o;
            #pragma unroll
            for (int mm = 0; mm < 8; ++mm)
                o[mm] = (short)vt[j * 16 + half * 8 + mm][e];
            *(bf16x8*)(dv + half * 8) = o;
        }
    }
}

// ---------------------------------------------------------------------------
// Kernel 3: flash attention.  grid = 768 blocks (3/CU), block = one (bh, qt);
// blocks c, c+256, c+512 form a balanced qt triple on the same CU.
// Swapped QK^T: sc = K*Q^T, lane owns q-row = llo; sc[kb][r] sits EXACTLY in
// the B-fragment layout of mfma_16x16x16 (k = kb*16 + lhi*4 + r), so PV runs
// fully in-register: acc[n] += mfma16x16(Vt-frag, P-frag).  C/D layout is
// identical to the 16x16x32 form -> acc/epilogue unchanged.
// Defer-max: skip rescale unless per-row max grows by > 8 (exp2 domain).
// ---------------------------------------------------------------------------
__global__ __launch_bounds__(256) void attn(const unsigned short* __restrict__ Q,
                                            const unsigned short* __restrict__ K,
                                            const unsigned short* __restrict__ Vt,
                                            float* __restrict__ out) {
    __shared__ __align__(16) char smem[32768];  // K dbuf 16K | Vt dbuf 16K
    const int t = threadIdx.x, wave = t >> 6, lane = t & 63;
    const int lhi = lane >> 4, llo = lane & 15;
    const int sr0 = t >> 3, scb = (t & 7) * 16;
    const int bid = blockIdx.x;
    const int tt = bid & 31, grp = (bid >> 5) & 7, e3 = bid >> 8;
    const int qt = (e3 == 0) ? tt
                 : (e3 == 1) ? ((tt + 16) & 31)
                             : ((tt < 16) ? 30 - 2 * tt : 63 - 2 * tt);
    const int bh = grp * 3 + e3;
    const unsigned short* Qg = Q + (size_t)bh * 2048 * 64;
    const char* Kg = (const char*)(K + (size_t)bh * 2048 * 64);
    const char* Vg = (const char*)(Vt + (size_t)bh * 64 * 2048);

    const int q0 = qt * 64 + wave * 16;      // this wave's q-block; lane q = q0+llo
    bf16x8 qa[2];
    #pragma unroll
    for (int kk = 0; kk < 2; ++kk)
        qa[kk] = *(const bf16x8*)(Qg + (size_t)(q0 + llo) * 64 + kk * 32 + lhi * 8);

    f32x4 acc[4] = {};                       // O^T: acc[n][r] -> e = n*16+lhi*4+r, q = llo
    float m_r = -1e30f, l_r = 0.f;

    bf16x8 kreg[2], vreg[2];
    #pragma unroll
    for (int i = 0; i < 2; ++i) {            // prefetch tile 0
        int row = sr0 + i * 32;
        kreg[i] = *(const bf16x8*)(Kg + (size_t)row * 128 + scb);
        vreg[i] = *(const bf16x8*)(Vg + (size_t)row * 4096 + scb);
    }
    #pragma unroll
    for (int i = 0; i < 2; ++i) {
        int row = sr0 + i * 32;
        *(bf16x8*)(smem + sw(row, scb)) = kreg[i];
        *(bf16x8*)(smem + 16384 + sw(row, scb)) = vreg[i];
    }
    __syncthreads();

    int cur = 0;
    for (int kt = 0; kt <= qt; ++kt) {
        if (kt < qt) {  // issue next-tile loads early (hide under compute, T14)
            const int k0 = (kt + 1) * 64;
            #pragma unroll
            for (int i = 0; i < 2; ++i) {
                int row = sr0 + i * 32;
                kreg[i] = *(const bf16x8*)(Kg + (size_t)(k0 + row) * 128 + scb);
                vreg[i] = *(const bf16x8*)(Vg + (size_t)row * 4096 + k0 * 2 + scb);
            }
        }
        char* Kb = smem + cur * 8192;
        char* Vb = smem + 16384 + cur * 8192;

        // S^T = K Q^T: sc[n][r] -> k-pos = n*16+lhi*4+r, q = llo
        f32x4 sc[4];
        __builtin_amdgcn_s_setprio(1);
        #pragma unroll
        for (int n = 0; n < 4; ++n) {
            f32x4 z = {};
            #pragma unroll
            for (int kk = 0; kk < 2; ++kk) {
                bf16x8 bk = *(const bf16x8*)(Kb + sw(n * 16 + llo, kk * 64 + lhi * 16));
                z = MFMA16(bk, qa[kk], z);
            }
            sc[n] = z;
        }
        __builtin_amdgcn_s_setprio(0);
        if (kt == qt) {   // causal mask, diagonal tile only
            #pragma unroll
            for (int n = 0; n < 4; ++n)
                #pragma unroll
                for (int r = 0; r < 4; ++r)
                    if (kt * 64 + n * 16 + lhi * 4 + r > q0 + llo) sc[n][r] = -1e30f;
        }
        // per-lane max over this lane's 16 scores
        float pmax = fmaxf(
            fmaxf(fmaxf(fmaxf(sc[0][0], sc[0][1]), fmaxf(sc[0][2], sc[0][3])),
                  fmaxf(fmaxf(sc[1][0], sc[1][1]), fmaxf(sc[1][2], sc[1][3]))),
            fmaxf(fmaxf(fmaxf(sc[2][0], sc[2][1]), fmaxf(sc[2][2], sc[2][3])),
                  fmaxf(fmaxf(sc[3][0], sc[3][1]), fmaxf(sc[3][2], sc[3][3]))));
        // defer-max: rescale only if some row's max grew by > 8 (exp2 units)
        if (__any(pmax > m_r + 8.0f)) {
            float tm = fmaxf(pmax, __shfl_xor(pmax, 16, 64));
            tm = fmaxf(tm, __shfl_xor(tm, 32, 64));   // row max across lhi groups
            float nm = fmaxf(m_r, tm);
            float corr = exp2f(m_r - nm);             // first tile: -> 0
            m_r = nm;
            l_r *= corr;
            #pragma unroll
            for (int n = 0; n < 4; ++n)
                #pragma unroll
                for (int r = 0; r < 4; ++r) acc[n][r] *= corr;
        }
        // P = exp2(sc - m_r), packed straight into mfma16x16 B-fragments
        bf16x4 pf[4];
        float ps = 0.f;
        #pragma unroll
        for (int kb = 0; kb < 4; ++kb) {
            float p0 = exp2f(sc[kb][0] - m_r), p1 = exp2f(sc[kb][1] - m_r);
            float p2 = exp2f(sc[kb][2] - m_r), p3 = exp2f(sc[kb][3] - m_r);
            ps += (p0 + p1) + (p2 + p3);
            unsigned int w0, w1;
            asm("v_cvt_pk_bf16_f32 %0, %1, %2" : "=v"(w0) : "v"(p0), "v"(p1));
            asm("v_cvt_pk_bf16_f32 %0, %1, %2" : "=v"(w1) : "v"(p2), "v"(p3));
            unsigned long long u = ((unsigned long long)w1 << 32) | w0;
            pf[kb] = __builtin_bit_cast(bf16x4, u);
        }
        l_r += ps;   // cross-lhi sum deferred to epilogue
        // O^T += V^T P  (in-register P; A = Vt b64 fragments)
        __builtin_amdgcn_s_setprio(1);
        #pragma unroll
        for (int n = 0; n < 4; ++n) {
            f32x4 a = acc[n];
            #pragma unroll
            for (int kb = 0; kb < 4; ++kb) {
                bf16x4 vf = *(const bf16x4*)(Vb + sw(n * 16 + llo, kb * 32 + lhi * 8));
                a = MFMAK16(vf, pf[kb], a);
            }
            acc[n] = a;
        }
        __builtin_amdgcn_s_setprio(0);
        if (kt < qt) {  // write next tile into the other buffer
            char* Kw = smem + (cur ^ 1) * 8192;
            char* Vw = smem + 16384 + (cur ^ 1) * 8192;
            #pragma unroll
            for (int i = 0; i < 2; ++i) {
                int row = sr0 + i * 32;
                *(bf16x8*)(Kw + sw(row, scb)) = kreg[i];
                *(bf16x8*)(Vw + sw(row, scb)) = vreg[i];
            }
        }
        __syncthreads();
        cur ^= 1;
    }
    // finish the deferred l reduction (4 lhi partials of row q=llo)
    l_r += __shfl_xor(l_r, 16, 64);
    l_r += __shfl_xor(l_r, 32, 64);
    const float inv = 1.0f / l_r;
    const int b = bh / 12, h = bh - b * 12;
    #pragma unroll
    for (int n = 0; n < 4; ++n) {
        float4 o;
        o.x = acc[n][0] * inv; o.y = acc[n][1] * inv;
        o.z = acc[n][2] * inv; o.w = acc[n][3] * inv;
        *(float4*)(out + (size_t)(b * 2048 + q0 + llo) * 768 + h * 64 + n * 16 + lhi * 4) = o;
    }
}

// ---------------------------------------------------------------------------
extern "C" void kernel_launch(void* const* d_in, const int* in_sizes, int n_in,
                              void* d_out, int out_size, void* d_ws, size_t ws_size,
                              hipStream_t stream) {
    const float* x  = (const float*)d_in[0];
    const float* Wq = (const float*)d_in[1];
    const float* Wk = (const float*)d_in[2];
    const float* Wv = (const float*)d_in[3];
    float* out = (float*)d_out;

    char* ws = (char*)d_ws;
    unsigned short* wt = (unsigned short*)(ws);
    unsigned short* q  = (unsigned short*)(ws + 3538944);
    unsigned short* k  = (unsigned short*)(ws + 9830400);
    unsigned short* vt = (unsigned short*)(ws + 16121856);
    // requires ws_size >= 22413312 bytes

    hipLaunchKernelGGL(prep_wt, dim3(36), dim3(256), 0, stream, Wq, Wk, Wv, wt);
    hipLaunchKernelGGL(proj_qkv, dim3(64, 12), dim3(256), 0, stream, x, wt, q, k, vt);
    hipLaunchKernelGGL(attn, dim3(768), dim3(256), 0, stream, q, k, vt, out);
}